// Round 12
// baseline (236.473 us; speedup 1.0000x reference)
//
#include <hip/hip_runtime.h>
#include <math.h>

#define B_   8
#define N_   4096
#define M_   256
#define KNN_ 3

// ---- workspace layout (float element offsets) ----
#define OFF_COUNTS   0          // [8][256] f32 (written by prep, read by build_fin2)
#define OFF_CM       8192       // [8][3][256] f32
#define OFF_NODEMAX  14336      // [8][256][384] f32 (atomicMax as int) ; H0 aliases (phase2)
#define OFF_H0       14336      // ushort [2048][512]
#define OFF_FIRST0   800768     // [8][384] f32
#define OFF_KNN      807944     // [8][4096][3] int ; CAT aliases (phase2)
#define OFF_CAT      807944     // ushort [2048][1184]
#define OFF_SORTED   906248     // [8][12288] int
#define OFF_MSORT    1004552    // [8][12288] int
#define OFF_FIN2     2020360    // ushort [2048][416] ; H1 aliases
#define OFF_H1       2020360    // ushort [2048][512]
#define OFF_WBF      2544648    // bf16 weights (ushort)
#define OFF_W3X      3661832    // f32x4 [384] (W3 cols 256..258)
// bf16 padded weight offsets (USHORT units, relative to wb base; contiguous)
#define O_W0 0         // 64   x 32
#define O_W1 2048      // 128  x 64
#define O_W2 10240     // 256  x 128
#define O_W3 43008     // 384  x 288
#define O_V0 153600    // 512  x 416
#define O_V1 366592    // 512  x 512
#define O_V2 628736    // 768  x 512
#define O_V3 1021952   // 1024 x 1184
#define W_TOTAL 2234368

typedef short  bf16x8 __attribute__((ext_vector_type(8)));
typedef float  f32x4  __attribute__((ext_vector_type(4)));
typedef float  f32x16 __attribute__((ext_vector_type(16)));

__device__ __forceinline__ unsigned short f2b(float f) {
    unsigned u = __float_as_uint(f);
    return (unsigned short)((u + 0x7FFFu + ((u >> 16) & 1u)) >> 16);
}
// HW packed bf16 convert (RNE), 2 f32 -> 1 dword
__device__ __forceinline__ unsigned cvt2(float lo, float hi) {
    unsigned r;
    asm("v_cvt_pk_bf16_f32 %0, %1, %2" : "=v"(r) : "v"(lo), "v"(hi));
    return r;
}
__device__ __forceinline__ f32x16 zero16() {
    f32x16 z;
    #pragma unroll
    for (int i = 0; i < 16; i++) z[i] = 0.f;
    return z;
}

// fused: blocks 0..127 = KNN assign (NO atomics); blocks 128+ = weight pad/convert + w3x
__global__ __launch_bounds__(256) void knn_setup(
        const float* __restrict__ x, const float* __restrict__ node,
        int* __restrict__ knn,
        const float* s0, const float* s1, const float* s2, const float* s3,
        const float* s4, const float* s5, const float* s6, const float* s7,
        unsigned short* __restrict__ dst, float* __restrict__ w3x) {
    __shared__ float nd0[M_], nd1[M_], nd2[M_], nn2[M_];
    int t = threadIdx.x;
    if (blockIdx.x < 128) {
        int b = blockIdx.x >> 4, xblk = blockIdx.x & 15;
        {
            float c0 = node[(b * 3 + 0) * M_ + t];
            float c1 = node[(b * 3 + 1) * M_ + t];
            float c2 = node[(b * 3 + 2) * M_ + t];
            nd0[t] = c0; nd1[t] = c1; nd2[t] = c2;
            nn2[t] = c0 * c0 + c1 * c1 + c2 * c2;
        }
        __syncthreads();
        int n = xblk * 256 + t;
        float x0 = x[(b * 3 + 0) * N_ + n];
        float x1 = x[(b * 3 + 1) * N_ + n];
        float x2 = x[(b * 3 + 2) * N_ + n];
        float xx = x0 * x0 + x1 * x1 + x2 * x2;
        float d0 = 1e30f, d1 = 1e30f, d2b = 1e30f;
        int i0 = 0, i1 = 0, i2 = 0;
        for (int m = 0; m < M_; m++) {
            float cross = x0 * nd0[m] + x1 * nd1[m] + x2 * nd2[m];
            float d = xx + nn2[m] - 2.f * cross;
            bool c0 = d < d0, c1 = d < d1, c2 = d < d2b;
            d2b = c1 ? d1 : (c2 ? d : d2b);
            i2  = c1 ? i1 : (c2 ? m : i2);
            d1  = c0 ? d0 : (c1 ? d : d1);
            i1  = c0 ? i0 : (c1 ? m : i1);
            d0  = c0 ? d  : d0;
            i0  = c0 ? m  : i0;
        }
        int base = (b * N_ + n) * 3;
        knn[base + 0] = i0; knn[base + 1] = i1; knn[base + 2] = i2;
    } else {
        int i = (blockIdx.x - 128) * 256 + t;
        int st = (gridDim.x - 128) * 256;
        for (int j = i; j < 1536; j += st) {
            int ch = j >> 2, c = j & 3;
            w3x[j] = (c < 3) ? s3[ch * 259 + 256 + c] : 0.f;
        }
        for (; i < W_TOTAL; i += st) {
            unsigned short v;
            if (i < O_W1) {
                int loc = i, co = loc >> 5, k = loc & 31;
                v = (k < 3) ? f2b(s0[co * 3 + k]) : (unsigned short)0;
            } else if (i < O_W2) {
                int loc = i - O_W1, co = loc >> 6, k = loc & 63;
                v = f2b(s1[co * 64 + k]);
            } else if (i < O_W3) {
                int loc = i - O_W2, co = loc >> 7, k = loc & 127;
                v = f2b(s2[co * 128 + k]);
            } else if (i < O_V0) {
                int loc = i - O_W3, co = loc / 288u, k = loc - co * 288;
                v = (k < 259) ? f2b(s3[co * 259 + k]) : (unsigned short)0;
            } else if (i < O_V1) {
                int loc = i - O_V0, co = loc / 416u, k = loc - co * 416;
                v = (k < 387) ? f2b(s4[co * 387 + k]) : (unsigned short)0;
            } else if (i < O_V2) {
                int loc = i - O_V1, co = loc >> 9, k = loc & 511;
                v = f2b(s5[co * 512 + k]);
            } else if (i < O_V3) {
                int loc = i - O_V2, co = loc >> 9, k = loc & 511;
                v = f2b(s6[co * 512 + k]);
            } else {
                int loc = i - O_V3, co = loc / 1184u, k = loc - co * 1184;
                v = (k < 1155) ? f2b(s7[co * 1155 + k]) : (unsigned short)0;
            }
            dst[i] = v;
        }
    }
}

// merged: LDS histogram (counts+sums, no global atomics) + cmean + scan +
// counting-sort scatter. 1 block per batch.
__global__ __launch_bounds__(256) void prep(const float* __restrict__ x,
        const int* __restrict__ knn, float* __restrict__ counts_g,
        float* __restrict__ cm, int* __restrict__ sorted, int* __restrict__ msort) {
    __shared__ float hs0[256], hs1[256], hs2[256];
    __shared__ int hc[256], tmp[256], offsL[257], cur[256];
    int t = threadIdx.x, b = blockIdx.x;
    hs0[t] = 0.f; hs1[t] = 0.f; hs2[t] = 0.f; hc[t] = 0; cur[t] = 0;
    __syncthreads();
    for (int e = t; e < KNN_ * N_; e += 256) {
        int n = e & (N_ - 1), k = e >> 12;
        int m = knn[(b * N_ + n) * 3 + k];
        (void)k;
        atomicAdd(&hc[m], 1);
        atomicAdd(&hs0[m], x[(b * 3 + 0) * N_ + n]);
        atomicAdd(&hs1[m], x[(b * 3 + 1) * N_ + n]);
        atomicAdd(&hs2[m], x[(b * 3 + 2) * N_ + n]);
    }
    __syncthreads();
    int v = hc[t];
    float cnt = (float)v;
    counts_g[b * M_ + t] = cnt;
    float inv = 1.f / (cnt + 1e-5f);
    cm[(b * 3 + 0) * M_ + t] = hs0[t] * inv;
    cm[(b * 3 + 1) * M_ + t] = hs1[t] * inv;
    cm[(b * 3 + 2) * M_ + t] = hs2[t] * inv;
    tmp[t] = v;
    __syncthreads();
    for (int off = 1; off < 256; off <<= 1) {
        int u = (t >= off) ? tmp[t - off] : 0;
        __syncthreads();
        tmp[t] += u;
        __syncthreads();
    }
    offsL[t] = tmp[t] - v;
    if (t == 255) offsL[256] = tmp[255];
    __syncthreads();
    for (int e = t; e < KNN_ * N_; e += 256) {
        int n = e & (N_ - 1), k = e >> 12;
        int m = knn[(b * N_ + n) * 3 + k];
        int pos = atomicAdd(&cur[m], 1);
        int dst = offsL[m] + pos;
        sorted[b * (KNN_ * N_) + dst] = e;
        msort[b * (KNN_ * N_) + dst] = m;
    }
}

// B-stationary layer: wave holds B-frags for ALL 4 p-tiles in regs,
// owns CTW co-tiles, streams W. 4 independent MFMA chains.
template<int KS, int INS, int OUTS, int CTW>
__device__ __forceinline__ void layerB(const unsigned short* __restrict__ Wg,
        const float* __restrict__ bias, const unsigned short* actin,
        unsigned short* actout, int wave, int lane) {
    int r = lane & 15, g = lane >> 4;
    bf16x8 bfr[4][KS];
    #pragma unroll
    for (int pt = 0; pt < 4; pt++) {
        const unsigned short* arow = actin + (pt * 16 + r) * INS + g * 8;
        #pragma unroll
        for (int ks = 0; ks < KS; ks++)
            bfr[pt][ks] = *(const bf16x8*)(arow + ks * 32);
    }
    #pragma unroll
    for (int c = 0; c < CTW; c++) {
        int ct = wave * CTW + c;
        const unsigned short* wrow = Wg + (ct * 16 + r) * (KS * 32) + g * 8;
        f32x4 acc[4];
        #pragma unroll
        for (int pt = 0; pt < 4; pt++) acc[pt] = (f32x4){0.f, 0.f, 0.f, 0.f};
        #pragma unroll
        for (int ks = 0; ks < KS; ks++) {
            bf16x8 wv = *(const bf16x8*)(wrow + ks * 32);
            #pragma unroll
            for (int pt = 0; pt < 4; pt++)
                acc[pt] = __builtin_amdgcn_mfma_f32_16x16x32_bf16(wv, bfr[pt][ks], acc[pt], 0, 0, 0);
        }
        f32x4 b4 = *(const f32x4*)(bias + ct * 16 + g * 4);
        #pragma unroll
        for (int pt = 0; pt < 4; pt++) {
            uint2 s;
            s.x = cvt2(fmaxf(acc[pt][0] + b4[0], 0.f), fmaxf(acc[pt][1] + b4[1], 0.f));
            s.y = cvt2(fmaxf(acc[pt][2] + b4[2], 0.f), fmaxf(acc[pt][3] + b4[3], 0.f));
            *(uint2*)(actout + (pt * 16 + r) * OUTS + ct * 16 + g * 4) = s;
        }
    }
}

// MFMA point-MLP over sorted entries, 64 points/block, ~52.5 KB LDS (3 blocks/CU).
// L4: swapped-operand 32x32x16 MFMA; seg-max in-register per lane.
__global__ __launch_bounds__(256, 3) void mlp1m(
        const float* __restrict__ x, const float* __restrict__ cm,
        const int* __restrict__ sorted, const int* __restrict__ msort,
        const unsigned short* __restrict__ wb, const float4* __restrict__ w3x,
        const float* __restrict__ bb0, const float* __restrict__ bb1,
        const float* __restrict__ bb2, const float* __restrict__ bb3,
        float* __restrict__ node_max, float* __restrict__ first0) {
    __shared__ __align__(16) char smem[50688];
    unsigned short* inb = (unsigned short*)smem;
    unsigned short* a1  = (unsigned short*)smem;
    unsigned short* a0  = (unsigned short*)(smem + 16896);
    unsigned short* cat = (unsigned short*)(smem + 16896);
    __shared__ float4 xdf[64];
    __shared__ int segm[65], segstart[66];
    __shared__ int nseg, p0loc;
    int t = threadIdx.x, b = blockIdx.y, lane = t & 63, wave = t >> 6;
    int e0 = blockIdx.x * 64;
    for (int e = t; e < 1280; e += 256) ((unsigned*)inb)[e] = 0u;   // zero inb [64][40]
    __syncthreads();
    if (t < 64) {   // wave 0: per-point init + ballot segment scan
        int p = t;
        if (p == 0) p0loc = -1;
        int j = sorted[b * 12288 + e0 + p];
        int m = msort[b * 12288 + e0 + p];
        int n = j & (N_ - 1);
        float xd0 = x[(b * 3 + 0) * N_ + n] - cm[(b * 3 + 0) * M_ + m];
        float xd1 = x[(b * 3 + 1) * N_ + n] - cm[(b * 3 + 1) * M_ + m];
        float xd2 = x[(b * 3 + 2) * N_ + n] - cm[(b * 3 + 2) * M_ + m];
        xdf[p] = make_float4(xd0, xd1, xd2, 0.f);
        inb[p * 40 + 0] = f2b(xd0);
        inb[p * 40 + 1] = f2b(xd1);
        inb[p * 40 + 2] = f2b(xd2);
        int prev = __shfl_up(m, 1);
        bool flag = (p == 0) || (m != prev);
        unsigned long long mk = __ballot(flag);
        int sid = __popcll(mk & ((1ull << p) - 1ull));
        if (flag) { segstart[sid] = p; segm[sid] = m; }
        if (p == 63) { int ns2 = __popcll(mk); nseg = ns2; segstart[ns2] = 64; }
        if (j == 0) p0loc = p;
    }
    __syncthreads();
    layerB<1, 40, 72, 1>(wb + O_W0, bb0, inb, a0, wave, lane);     // inb -> a0
    __syncthreads();
    layerB<2, 72, 132, 2>(wb + O_W1, bb1, a0, a1, wave, lane);     // a0 -> a1 (over inb)
    __syncthreads();
    layerB<4, 132, 264, 4>(wb + O_W2, bb2, a1, cat, wave, lane);   // a1 -> cat (over a0)
    __syncthreads();
    // ---- L4: 12 co-tiles of 32 x 4 waves (3 each), 2 point-halves, K=256 ----
    int l31 = lane & 31, half = lane >> 5;
    f32x16 acc[6];   // [c3*2 + ph]
    #pragma unroll
    for (int q = 0; q < 6; q++) acc[q] = zero16();
    {
        const unsigned short* arow0 = cat + l31 * 264 + half * 8;
        const unsigned short* arow1 = cat + (32 + l31) * 264 + half * 8;
        const unsigned short* wrowb = wb + O_W3 + (wave * 96 + l31) * 288 + half * 8;
        #pragma unroll
        for (int ks = 0; ks < 16; ks++) {
            bf16x8 aA = *(const bf16x8*)(arow0 + ks * 16);
            bf16x8 aB = *(const bf16x8*)(arow1 + ks * 16);
            #pragma unroll
            for (int c3 = 0; c3 < 3; c3++) {
                bf16x8 wv = *(const bf16x8*)(wrowb + c3 * 32 * 288 + ks * 16);
                acc[c3 * 2 + 0] = __builtin_amdgcn_mfma_f32_32x32x16_bf16(aA, wv, acc[c3 * 2 + 0], 0, 0, 0);
                acc[c3 * 2 + 1] = __builtin_amdgcn_mfma_f32_32x32x16_bf16(aB, wv, acc[c3 * 2 + 1], 0, 0, 0);
            }
        }
    }
    int ns = nseg, p0l = p0loc;
    float bias3[3]; float4 wx3[3];
    #pragma unroll
    for (int c3 = 0; c3 < 3; c3++) {
        bias3[c3] = bb3[(wave * 3 + c3) * 32 + l31];
        wx3[c3]   = w3x[(wave * 3 + c3) * 32 + l31];
    }
    #pragma unroll
    for (int ph = 0; ph < 2; ph++) {
        #pragma unroll
        for (int rg = 0; rg < 16; rg++) {
            int row = ph * 32 + (rg & 3) + 8 * (rg >> 2) + 4 * half;
            float4 xv = xdf[row];
            #pragma unroll
            for (int c3 = 0; c3 < 3; c3++) {
                float s = acc[c3 * 2 + ph][rg] + bias3[c3]
                        + wx3[c3].x * xv.x + wx3[c3].y * xv.y + wx3[c3].z * xv.z;
                acc[c3 * 2 + ph][rg] = fmaxf(s, 0.f);
            }
        }
    }
    if (p0l >= 0) {
        #pragma unroll
        for (int ph = 0; ph < 2; ph++)
            #pragma unroll
            for (int rg = 0; rg < 16; rg++) {
                int row = ph * 32 + (rg & 3) + 8 * (rg >> 2) + 4 * half;
                if (row == p0l) {
                    #pragma unroll
                    for (int c3 = 0; c3 < 3; c3++)
                        first0[b * 384 + (wave * 3 + c3) * 32 + l31] = acc[c3 * 2 + ph][rg];
                }
            }
    }
    for (int s = 0; s < ns; s++) {
        int s0 = segstart[s], s1 = segstart[s + 1];
        float m0 = 0.f, m1 = 0.f, m2 = 0.f;
        if (s0 < 32) {
            #pragma unroll
            for (int rg = 0; rg < 16; rg++) {
                int row = (rg & 3) + 8 * (rg >> 2) + 4 * half;
                bool in = (row >= s0) && (row < s1);
                m0 = fmaxf(m0, in ? acc[0][rg] : 0.f);
                m1 = fmaxf(m1, in ? acc[2][rg] : 0.f);
                m2 = fmaxf(m2, in ? acc[4][rg] : 0.f);
            }
        }
        if (s1 > 32) {
            #pragma unroll
            for (int rg = 0; rg < 16; rg++) {
                int row = 32 + (rg & 3) + 8 * (rg >> 2) + 4 * half;
                bool in = (row >= s0) && (row < s1);
                m0 = fmaxf(m0, in ? acc[1][rg] : 0.f);
                m1 = fmaxf(m1, in ? acc[3][rg] : 0.f);
                m2 = fmaxf(m2, in ? acc[5][rg] : 0.f);
            }
        }
        m0 = fmaxf(m0, __shfl_xor(m0, 32));
        m1 = fmaxf(m1, __shfl_xor(m1, 32));
        m2 = fmaxf(m2, __shfl_xor(m2, 32));
        if (lane < 32) {
            float* dstp = &node_max[(size_t)(b * M_ + segm[s]) * 384 + wave * 96];
            atomicMax((int*)(dstp + l31),      __float_as_int(m0));
            atomicMax((int*)(dstp + 32 + l31), __float_as_int(m1));
            atomicMax((int*)(dstp + 64 + l31), __float_as_int(m2));
        }
    }
}

// masked node features -> bf16 fin2 [2048][416] and cat tail cols 768..1183
__global__ void build_fin2(const float* __restrict__ cm, const float* __restrict__ counts,
                           const float* __restrict__ nmax, const float* __restrict__ first0,
                           unsigned short* __restrict__ fin2, unsigned short* __restrict__ cat) {
    int tot = 2048 * 416;
    int i = blockIdx.x * blockDim.x + threadIdx.x;
    int st = gridDim.x * blockDim.x;
    for (; i < tot; i += st) {
        int n = i / 416, ch = i - n * 416;
        int b = n >> 8, m = n & 255;
        float v = 0.f;
        if (ch < 3) v = cm[(b * 3 + ch) * M_ + m];
        else if (ch < 387)
            v = (counts[n] > 0.f) ? nmax[(size_t)n * 384 + (ch - 3)]
                                  : first0[b * 384 + (ch - 3)];
        unsigned short u = f2b(v);
        fin2[n * 416 + ch] = u;
        cat[(size_t)n * 1184 + 768 + ch] = u;
    }
}

// node-MLP layer: one wave = 4 co-tiles sharing one act-frag set (4 indep chains)
template<int KS, int CTQ>
__global__ __launch_bounds__(256, 2) void nlayer4(const unsigned short* __restrict__ W,
        const float* __restrict__ bias, const unsigned short* __restrict__ actin,
        unsigned short* __restrict__ actout, int outs) {
    int wave = threadIdx.x >> 6, lane = threadIdx.x & 63;
    int id = blockIdx.x * 4 + wave;
    int nt = id / CTQ, cq = id - nt * CTQ;
    int r = lane & 15, g = lane >> 4;
    const unsigned short* arow = actin + (size_t)(nt * 16 + r) * (KS * 32) + g * 8;
    bf16x8 afr[KS];
    #pragma unroll
    for (int ks = 0; ks < KS; ks++) afr[ks] = *(const bf16x8*)(arow + ks * 32);
    const unsigned short* w0 = W + (cq * 64 + r) * (KS * 32) + g * 8;
    f32x4 acc[4];
    #pragma unroll
    for (int c = 0; c < 4; c++) acc[c] = (f32x4){0.f, 0.f, 0.f, 0.f};
    #pragma unroll
    for (int ks = 0; ks < KS; ks++) {
        #pragma unroll
        for (int c = 0; c < 4; c++) {
            bf16x8 wv = *(const bf16x8*)(w0 + c * 16 * KS * 32 + ks * 32);
            acc[c] = __builtin_amdgcn_mfma_f32_16x16x32_bf16(wv, afr[ks], acc[c], 0, 0, 0);
        }
    }
    #pragma unroll
    for (int c = 0; c < 4; c++) {
        f32x4 b4 = *(const f32x4*)(bias + cq * 64 + c * 16 + g * 4);
        uint2 s;
        s.x = cvt2(fmaxf(acc[c][0] + b4[0], 0.f), fmaxf(acc[c][1] + b4[1], 0.f));
        s.y = cvt2(fmaxf(acc[c][2] + b4[2], 0.f), fmaxf(acc[c][3] + b4[3], 0.f));
        *(uint2*)(actout + (size_t)(nt * 16 + r) * outs + cq * 64 + c * 16 + g * 4) = s;
    }
}

// last node layer, STREAMING (no act residency -> no spill):
// wave = 16 nodes x 32 couts (2 chains), K=1184 streamed; + global max over nodes
__global__ __launch_bounds__(256) void nlayer_max_s(const unsigned short* __restrict__ W,
        const float* __restrict__ bias, const unsigned short* __restrict__ actin,
        float* __restrict__ out) {
    int wave = threadIdx.x >> 6, lane = threadIdx.x & 63;
    int id = blockIdx.x * 4 + wave;          // 4096 waves
    int nt = id >> 5, cp = id & 31;          // nt: 0..127 (16 nodes), cp: 0..31 (32 couts)
    int r = lane & 15, g = lane >> 4;
    const unsigned short* arow = actin + (size_t)(nt * 16 + r) * 1184 + g * 8;
    const unsigned short* w0 = W + (size_t)(cp * 32 + r) * 1184 + g * 8;
    const unsigned short* w1 = w0 + 16 * 1184;
    f32x4 a0 = {0.f, 0.f, 0.f, 0.f}, a1 = {0.f, 0.f, 0.f, 0.f};
    #pragma unroll 4
    for (int ks = 0; ks < 37; ks++) {
        bf16x8 av = *(const bf16x8*)(arow + ks * 32);
        a0 = __builtin_amdgcn_mfma_f32_16x16x32_bf16(*(const bf16x8*)(w0 + ks * 32), av, a0, 0, 0, 0);
        a1 = __builtin_amdgcn_mfma_f32_16x16x32_bf16(*(const bf16x8*)(w1 + ks * 32), av, a1, 0, 0, 0);
    }
    int b = nt >> 4;
    #pragma unroll
    for (int c = 0; c < 2; c++) {
        f32x4 acc = c ? a1 : a0;
        f32x4 b4 = *(const f32x4*)(bias + cp * 32 + c * 16 + g * 4);
        #pragma unroll
        for (int i = 0; i < 4; i++) {
            float v = fmaxf(acc[i] + b4[i], 0.f);
            v = fmaxf(v, __shfl_xor(v, 1));
            v = fmaxf(v, __shfl_xor(v, 2));
            v = fmaxf(v, __shfl_xor(v, 4));
            v = fmaxf(v, __shfl_xor(v, 8));
            if (r == 0)
                atomicMax((int*)&out[b * 1024 + cp * 32 + c * 16 + g * 4 + i],
                          __float_as_int(v));
        }
    }
}

extern "C" void kernel_launch(void* const* d_in, const int* in_sizes, int n_in,
                              void* d_out, int out_size, void* d_ws, size_t ws_size,
                              hipStream_t stream) {
    (void)in_sizes; (void)n_in; (void)out_size; (void)ws_size;
    const float* x    = (const float*)d_in[0];
    const float* node = (const float*)d_in[2];
    const float* fpw[4] = {(const float*)d_in[4], (const float*)d_in[6],
                           (const float*)d_in[8], (const float*)d_in[10]};
    const float* fpb[4] = {(const float*)d_in[5], (const float*)d_in[7],
                           (const float*)d_in[9], (const float*)d_in[11]};
    const float* fnw[4] = {(const float*)d_in[12], (const float*)d_in[14],
                           (const float*)d_in[16], (const float*)d_in[18]};
    const float* fnb[4] = {(const float*)d_in[13], (const float*)d_in[15],
                           (const float*)d_in[17], (const float*)d_in[19]};
    float* ws  = (float*)d_ws;
    float* out = (float*)d_out;
    unsigned short* wb   = (unsigned short*)(ws + OFF_WBF);
    unsigned short* fin2 = (unsigned short*)(ws + OFF_FIN2);
    unsigned short* h0   = (unsigned short*)(ws + OFF_H0);
    unsigned short* h1   = (unsigned short*)(ws + OFF_H1);
    unsigned short* catb = (unsigned short*)(ws + OFF_CAT);

    // zero only atomicMax targets: node_max + out
    hipMemsetAsync(ws + OFF_NODEMAX, 0, (size_t)(B_ * M_ * 384) * 4, stream);
    hipMemsetAsync(out, 0, (size_t)B_ * 1024 * 4, stream);

    knn_setup<<<128 + 2048, 256, 0, stream>>>(
        x, node, (int*)(ws + OFF_KNN),
        fpw[0], fpw[1], fpw[2], fpw[3], fnw[0], fnw[1], fnw[2], fnw[3],
        wb, ws + OFF_W3X);
    prep<<<B_, 256, 0, stream>>>(
        x, (int*)(ws + OFF_KNN), ws + OFF_COUNTS,
        ws + OFF_CM, (int*)(ws + OFF_SORTED), (int*)(ws + OFF_MSORT));
    mlp1m<<<dim3(KNN_ * N_ / 64, B_), 256, 0, stream>>>(
        x, ws + OFF_CM, (int*)(ws + OFF_SORTED), (int*)(ws + OFF_MSORT), wb,
        (const float4*)(ws + OFF_W3X),
        fpb[0], fpb[1], fpb[2], fpb[3], ws + OFF_NODEMAX, ws + OFF_FIRST0);
    build_fin2<<<3328, 256, 0, stream>>>(
        ws + OFF_CM, ws + OFF_COUNTS, ws + OFF_NODEMAX, ws + OFF_FIRST0, fin2, catb);
    nlayer4<13, 8><<<256,  256, 0, stream>>>(wb + O_V0, fnb[0], fin2, h0, 512);
    nlayer4<16, 8><<<256,  256, 0, stream>>>(wb + O_V1, fnb[1], h0, h1, 512);
    nlayer4<16, 12><<<384, 256, 0, stream>>>(wb + O_V2, fnb[2], h1, catb, 1184);
    nlayer_max_s<<<1024, 256, 0, stream>>>(wb + O_V3, fnb[3], catb, out);
}

// Round 13
// 201.345 us; speedup vs baseline: 1.1745x; 1.1745x over previous
//
#include <hip/hip_runtime.h>
#include <math.h>

#define B_   8
#define N_   4096
#define M_   256
#define KNN_ 3

// ---- workspace layout (float element offsets) ----
#define OFF_COUNTS   0          // [8][256] f32
#define OFF_SUMS     2048       // [8][256][3] f32
#define OFF_CM       8192       // [8][3][256] f32
#define OFF_NODEMAX  14336      // [8][256][384] f32 (atomicMax as int) ; H0 aliases (phase2)
#define OFF_H0       14336      // ushort [2048][512]
#define OFF_FIRST0   800768     // [8][384] f32
#define ZERO_COUNT   803840     // memset range (floats)
#define OFF_KNN      807944     // [8][4096][3] int ; CAT aliases (phase2)
#define OFF_CAT      807944     // ushort [2048][1184]
#define OFF_SORTED   906248     // [8][12288] int
#define OFF_MSORT    1004552    // [8][12288] int
#define OFF_FIN2     2020360    // ushort [2048][416] ; H1 aliases
#define OFF_H1       2020360    // ushort [2048][512]
#define OFF_WBF      2544648    // bf16 weights (ushort)
#define OFF_W3X      3661832    // f32x4 [384] (W3 cols 256..258)
// bf16 padded weight offsets (USHORT units, relative to wb base; contiguous)
#define O_W0 0         // 64   x 32
#define O_W1 2048      // 128  x 64
#define O_W2 10240     // 256  x 128
#define O_W3 43008     // 384  x 288
#define O_V0 153600    // 512  x 416
#define O_V1 366592    // 512  x 512
#define O_V2 628736    // 768  x 512
#define O_V3 1021952   // 1024 x 1184
#define W_TOTAL 2234368

typedef short  bf16x8 __attribute__((ext_vector_type(8)));
typedef float  f32x4  __attribute__((ext_vector_type(4)));
typedef float  f32x16 __attribute__((ext_vector_type(16)));

__device__ __forceinline__ unsigned short f2b(float f) {
    unsigned u = __float_as_uint(f);
    return (unsigned short)((u + 0x7FFFu + ((u >> 16) & 1u)) >> 16);
}
// HW packed bf16 convert (RNE), 2 f32 -> 1 dword
__device__ __forceinline__ unsigned cvt2(float lo, float hi) {
    unsigned r;
    asm("v_cvt_pk_bf16_f32 %0, %1, %2" : "=v"(r) : "v"(lo), "v"(hi));
    return r;
}
__device__ __forceinline__ f32x16 zero16() {
    f32x16 z;
    #pragma unroll
    for (int i = 0; i < 16; i++) z[i] = 0.f;
    return z;
}

// fused: blocks 0..127 = KNN assign (global atomics, 128-block distributed);
// blocks 128+ = weight pad/convert + w3x
__global__ __launch_bounds__(256) void knn_setup(
        const float* __restrict__ x, const float* __restrict__ node,
        int* __restrict__ knn, float* __restrict__ counts, float* __restrict__ sums,
        const float* s0, const float* s1, const float* s2, const float* s3,
        const float* s4, const float* s5, const float* s6, const float* s7,
        unsigned short* __restrict__ dst, float* __restrict__ w3x) {
    __shared__ float nd0[M_], nd1[M_], nd2[M_], nn2[M_];
    int t = threadIdx.x;
    if (blockIdx.x < 128) {
        int b = blockIdx.x >> 4, xblk = blockIdx.x & 15;
        {
            float c0 = node[(b * 3 + 0) * M_ + t];
            float c1 = node[(b * 3 + 1) * M_ + t];
            float c2 = node[(b * 3 + 2) * M_ + t];
            nd0[t] = c0; nd1[t] = c1; nd2[t] = c2;
            nn2[t] = c0 * c0 + c1 * c1 + c2 * c2;
        }
        __syncthreads();
        int n = xblk * 256 + t;
        float x0 = x[(b * 3 + 0) * N_ + n];
        float x1 = x[(b * 3 + 1) * N_ + n];
        float x2 = x[(b * 3 + 2) * N_ + n];
        float xx = x0 * x0 + x1 * x1 + x2 * x2;
        float d0 = 1e30f, d1 = 1e30f, d2b = 1e30f;
        int i0 = 0, i1 = 0, i2 = 0;
        for (int m = 0; m < M_; m++) {
            float cross = x0 * nd0[m] + x1 * nd1[m] + x2 * nd2[m];
            float d = xx + nn2[m] - 2.f * cross;
            bool c0 = d < d0, c1 = d < d1, c2 = d < d2b;
            d2b = c1 ? d1 : (c2 ? d : d2b);
            i2  = c1 ? i1 : (c2 ? m : i2);
            d1  = c0 ? d0 : (c1 ? d : d1);
            i1  = c0 ? i0 : (c1 ? m : i1);
            d0  = c0 ? d  : d0;
            i0  = c0 ? m  : i0;
        }
        int base = (b * N_ + n) * 3;
        knn[base + 0] = i0; knn[base + 1] = i1; knn[base + 2] = i2;
        int mm[3] = {i0, i1, i2};
        #pragma unroll
        for (int k = 0; k < 3; k++) {
            int m = mm[k];
            atomicAdd(&counts[b * M_ + m], 1.f);
            atomicAdd(&sums[(b * M_ + m) * 3 + 0], x0);
            atomicAdd(&sums[(b * M_ + m) * 3 + 1], x1);
            atomicAdd(&sums[(b * M_ + m) * 3 + 2], x2);
        }
    } else {
        int i = (blockIdx.x - 128) * 256 + t;
        int st = (gridDim.x - 128) * 256;
        for (int j = i; j < 1536; j += st) {
            int ch = j >> 2, c = j & 3;
            w3x[j] = (c < 3) ? s3[ch * 259 + 256 + c] : 0.f;
        }
        for (; i < W_TOTAL; i += st) {
            unsigned short v;
            if (i < O_W1) {
                int loc = i, co = loc >> 5, k = loc & 31;
                v = (k < 3) ? f2b(s0[co * 3 + k]) : (unsigned short)0;
            } else if (i < O_W2) {
                int loc = i - O_W1, co = loc >> 6, k = loc & 63;
                v = f2b(s1[co * 64 + k]);
            } else if (i < O_W3) {
                int loc = i - O_W2, co = loc >> 7, k = loc & 127;
                v = f2b(s2[co * 128 + k]);
            } else if (i < O_V0) {
                int loc = i - O_W3, co = loc / 288u, k = loc - co * 288;
                v = (k < 259) ? f2b(s3[co * 259 + k]) : (unsigned short)0;
            } else if (i < O_V1) {
                int loc = i - O_V0, co = loc / 416u, k = loc - co * 416;
                v = (k < 387) ? f2b(s4[co * 387 + k]) : (unsigned short)0;
            } else if (i < O_V2) {
                int loc = i - O_V1, co = loc >> 9, k = loc & 511;
                v = f2b(s5[co * 512 + k]);
            } else if (i < O_V3) {
                int loc = i - O_V2, co = loc >> 9, k = loc & 511;
                v = f2b(s6[co * 512 + k]);
            } else {
                int loc = i - O_V3, co = loc / 1184u, k = loc - co * 1184;
                v = (k < 1155) ? f2b(s7[co * 1155 + k]) : (unsigned short)0;
            }
            dst[i] = v;
        }
    }
}

// merged: cluster means + scan + counting-sort scatter (LDS cursors), 1 block/batch
__global__ __launch_bounds__(256) void prep(const float* __restrict__ counts,
        const float* __restrict__ sums, const int* __restrict__ knn,
        float* __restrict__ cm, int* __restrict__ sorted, int* __restrict__ msort) {
    __shared__ int tmp[256], offsL[257], cur[256];
    int t = threadIdx.x, b = blockIdx.x;
    float cnt = counts[b * M_ + t];
    float inv = 1.f / (cnt + 1e-5f);
    #pragma unroll
    for (int c = 0; c < 3; c++)
        cm[(b * 3 + c) * M_ + t] = sums[(b * M_ + t) * 3 + c] * inv;
    int v = (int)cnt;
    tmp[t] = v; cur[t] = 0;
    __syncthreads();
    for (int off = 1; off < 256; off <<= 1) {
        int u = (t >= off) ? tmp[t - off] : 0;
        __syncthreads();
        tmp[t] += u;
        __syncthreads();
    }
    offsL[t] = tmp[t] - v;
    if (t == 255) offsL[256] = tmp[255];
    __syncthreads();
    for (int e = t; e < KNN_ * N_; e += 256) {
        int n = e & (N_ - 1), k = e >> 12;
        int m = knn[(b * N_ + n) * 3 + k];
        int pos = atomicAdd(&cur[m], 1);
        int dst = offsL[m] + pos;
        sorted[b * (KNN_ * N_) + dst] = e;
        msort[b * (KNN_ * N_) + dst] = m;
    }
}

// B-stationary layer: wave holds B-frags for ALL 4 p-tiles in regs,
// owns CTW co-tiles, streams W. 4 independent MFMA chains.
template<int KS, int INS, int OUTS, int CTW>
__device__ __forceinline__ void layerB(const unsigned short* __restrict__ Wg,
        const float* __restrict__ bias, const unsigned short* actin,
        unsigned short* actout, int wave, int lane) {
    int r = lane & 15, g = lane >> 4;
    bf16x8 bfr[4][KS];
    #pragma unroll
    for (int pt = 0; pt < 4; pt++) {
        const unsigned short* arow = actin + (pt * 16 + r) * INS + g * 8;
        #pragma unroll
        for (int ks = 0; ks < KS; ks++)
            bfr[pt][ks] = *(const bf16x8*)(arow + ks * 32);
    }
    #pragma unroll
    for (int c = 0; c < CTW; c++) {
        int ct = wave * CTW + c;
        const unsigned short* wrow = Wg + (ct * 16 + r) * (KS * 32) + g * 8;
        f32x4 acc[4];
        #pragma unroll
        for (int pt = 0; pt < 4; pt++) acc[pt] = (f32x4){0.f, 0.f, 0.f, 0.f};
        #pragma unroll
        for (int ks = 0; ks < KS; ks++) {
            bf16x8 wv = *(const bf16x8*)(wrow + ks * 32);
            #pragma unroll
            for (int pt = 0; pt < 4; pt++)
                acc[pt] = __builtin_amdgcn_mfma_f32_16x16x32_bf16(wv, bfr[pt][ks], acc[pt], 0, 0, 0);
        }
        f32x4 b4 = *(const f32x4*)(bias + ct * 16 + g * 4);
        #pragma unroll
        for (int pt = 0; pt < 4; pt++) {
            uint2 s;
            s.x = cvt2(fmaxf(acc[pt][0] + b4[0], 0.f), fmaxf(acc[pt][1] + b4[1], 0.f));
            s.y = cvt2(fmaxf(acc[pt][2] + b4[2], 0.f), fmaxf(acc[pt][3] + b4[3], 0.f));
            *(uint2*)(actout + (pt * 16 + r) * OUTS + ct * 16 + g * 4) = s;
        }
    }
}

// MFMA point-MLP over sorted entries, 64 points/block, ~52.5 KB LDS (3 blocks/CU).
// L4: swapped-operand 32x32x16 MFMA; seg-max in-register per lane.
__global__ __launch_bounds__(256, 3) void mlp1m(
        const float* __restrict__ x, const float* __restrict__ cm,
        const int* __restrict__ sorted, const int* __restrict__ msort,
        const unsigned short* __restrict__ wb, const float4* __restrict__ w3x,
        const float* __restrict__ bb0, const float* __restrict__ bb1,
        const float* __restrict__ bb2, const float* __restrict__ bb3,
        float* __restrict__ node_max, float* __restrict__ first0) {
    __shared__ __align__(16) char smem[50688];
    unsigned short* inb = (unsigned short*)smem;
    unsigned short* a1  = (unsigned short*)smem;
    unsigned short* a0  = (unsigned short*)(smem + 16896);
    unsigned short* cat = (unsigned short*)(smem + 16896);
    __shared__ float4 xdf[64];
    __shared__ int segm[65], segstart[66];
    __shared__ int nseg, p0loc;
    int t = threadIdx.x, b = blockIdx.y, lane = t & 63, wave = t >> 6;
    int e0 = blockIdx.x * 64;
    for (int e = t; e < 1280; e += 256) ((unsigned*)inb)[e] = 0u;   // zero inb [64][40]
    __syncthreads();
    if (t < 64) {   // wave 0: per-point init + ballot segment scan
        int p = t;
        if (p == 0) p0loc = -1;
        int j = sorted[b * 12288 + e0 + p];
        int m = msort[b * 12288 + e0 + p];
        int n = j & (N_ - 1);
        float xd0 = x[(b * 3 + 0) * N_ + n] - cm[(b * 3 + 0) * M_ + m];
        float xd1 = x[(b * 3 + 1) * N_ + n] - cm[(b * 3 + 1) * M_ + m];
        float xd2 = x[(b * 3 + 2) * N_ + n] - cm[(b * 3 + 2) * M_ + m];
        xdf[p] = make_float4(xd0, xd1, xd2, 0.f);
        inb[p * 40 + 0] = f2b(xd0);
        inb[p * 40 + 1] = f2b(xd1);
        inb[p * 40 + 2] = f2b(xd2);
        int prev = __shfl_up(m, 1);
        bool flag = (p == 0) || (m != prev);
        unsigned long long mk = __ballot(flag);
        int sid = __popcll(mk & ((1ull << p) - 1ull));
        if (flag) { segstart[sid] = p; segm[sid] = m; }
        if (p == 63) { int ns2 = __popcll(mk); nseg = ns2; segstart[ns2] = 64; }
        if (j == 0) p0loc = p;
    }
    __syncthreads();
    layerB<1, 40, 72, 1>(wb + O_W0, bb0, inb, a0, wave, lane);     // inb -> a0
    __syncthreads();
    layerB<2, 72, 132, 2>(wb + O_W1, bb1, a0, a1, wave, lane);     // a0 -> a1 (over inb)
    __syncthreads();
    layerB<4, 132, 264, 4>(wb + O_W2, bb2, a1, cat, wave, lane);   // a1 -> cat (over a0)
    __syncthreads();
    // ---- L4: 12 co-tiles of 32 x 4 waves (3 each), 2 point-halves, K=256 ----
    int l31 = lane & 31, half = lane >> 5;
    f32x16 acc[6];   // [c3*2 + ph]
    #pragma unroll
    for (int q = 0; q < 6; q++) acc[q] = zero16();
    {
        const unsigned short* arow0 = cat + l31 * 264 + half * 8;
        const unsigned short* arow1 = cat + (32 + l31) * 264 + half * 8;
        const unsigned short* wrowb = wb + O_W3 + (wave * 96 + l31) * 288 + half * 8;
        #pragma unroll
        for (int ks = 0; ks < 16; ks++) {
            bf16x8 aA = *(const bf16x8*)(arow0 + ks * 16);
            bf16x8 aB = *(const bf16x8*)(arow1 + ks * 16);
            #pragma unroll
            for (int c3 = 0; c3 < 3; c3++) {
                bf16x8 wv = *(const bf16x8*)(wrowb + c3 * 32 * 288 + ks * 16);
                acc[c3 * 2 + 0] = __builtin_amdgcn_mfma_f32_32x32x16_bf16(aA, wv, acc[c3 * 2 + 0], 0, 0, 0);
                acc[c3 * 2 + 1] = __builtin_amdgcn_mfma_f32_32x32x16_bf16(aB, wv, acc[c3 * 2 + 1], 0, 0, 0);
            }
        }
    }
    int ns = nseg, p0l = p0loc;
    float bias3[3]; float4 wx3[3];
    #pragma unroll
    for (int c3 = 0; c3 < 3; c3++) {
        bias3[c3] = bb3[(wave * 3 + c3) * 32 + l31];
        wx3[c3]   = w3x[(wave * 3 + c3) * 32 + l31];
    }
    #pragma unroll
    for (int ph = 0; ph < 2; ph++) {
        #pragma unroll
        for (int rg = 0; rg < 16; rg++) {
            int row = ph * 32 + (rg & 3) + 8 * (rg >> 2) + 4 * half;
            float4 xv = xdf[row];
            #pragma unroll
            for (int c3 = 0; c3 < 3; c3++) {
                float s = acc[c3 * 2 + ph][rg] + bias3[c3]
                        + wx3[c3].x * xv.x + wx3[c3].y * xv.y + wx3[c3].z * xv.z;
                acc[c3 * 2 + ph][rg] = fmaxf(s, 0.f);
            }
        }
    }
    if (p0l >= 0) {
        #pragma unroll
        for (int ph = 0; ph < 2; ph++)
            #pragma unroll
            for (int rg = 0; rg < 16; rg++) {
                int row = ph * 32 + (rg & 3) + 8 * (rg >> 2) + 4 * half;
                if (row == p0l) {
                    #pragma unroll
                    for (int c3 = 0; c3 < 3; c3++)
                        first0[b * 384 + (wave * 3 + c3) * 32 + l31] = acc[c3 * 2 + ph][rg];
                }
            }
    }
    for (int s = 0; s < ns; s++) {
        int s0 = segstart[s], s1 = segstart[s + 1];
        float m0 = 0.f, m1 = 0.f, m2 = 0.f;
        if (s0 < 32) {
            #pragma unroll
            for (int rg = 0; rg < 16; rg++) {
                int row = (rg & 3) + 8 * (rg >> 2) + 4 * half;
                bool in = (row >= s0) && (row < s1);
                m0 = fmaxf(m0, in ? acc[0][rg] : 0.f);
                m1 = fmaxf(m1, in ? acc[2][rg] : 0.f);
                m2 = fmaxf(m2, in ? acc[4][rg] : 0.f);
            }
        }
        if (s1 > 32) {
            #pragma unroll
            for (int rg = 0; rg < 16; rg++) {
                int row = 32 + (rg & 3) + 8 * (rg >> 2) + 4 * half;
                bool in = (row >= s0) && (row < s1);
                m0 = fmaxf(m0, in ? acc[1][rg] : 0.f);
                m1 = fmaxf(m1, in ? acc[3][rg] : 0.f);
                m2 = fmaxf(m2, in ? acc[5][rg] : 0.f);
            }
        }
        m0 = fmaxf(m0, __shfl_xor(m0, 32));
        m1 = fmaxf(m1, __shfl_xor(m1, 32));
        m2 = fmaxf(m2, __shfl_xor(m2, 32));
        if (lane < 32) {
            float* dstp = &node_max[(size_t)(b * M_ + segm[s]) * 384 + wave * 96];
            atomicMax((int*)(dstp + l31),      __float_as_int(m0));
            atomicMax((int*)(dstp + 32 + l31), __float_as_int(m1));
            atomicMax((int*)(dstp + 64 + l31), __float_as_int(m2));
        }
    }
}

// masked node features -> bf16 fin2 [2048][416] and cat tail cols 768..1183
__global__ void build_fin2(const float* __restrict__ cm, const float* __restrict__ counts,
                           const float* __restrict__ nmax, const float* __restrict__ first0,
                           unsigned short* __restrict__ fin2, unsigned short* __restrict__ cat) {
    int tot = 2048 * 416;
    int i = blockIdx.x * blockDim.x + threadIdx.x;
    int st = gridDim.x * blockDim.x;
    for (; i < tot; i += st) {
        int n = i / 416, ch = i - n * 416;
        int b = n >> 8, m = n & 255;
        float v = 0.f;
        if (ch < 3) v = cm[(b * 3 + ch) * M_ + m];
        else if (ch < 387)
            v = (counts[n] > 0.f) ? nmax[(size_t)n * 384 + (ch - 3)]
                                  : first0[b * 384 + (ch - 3)];
        unsigned short u = f2b(v);
        fin2[n * 416 + ch] = u;
        cat[(size_t)n * 1184 + 768 + ch] = u;
    }
}

// node-MLP layer: one wave = 2 co-tiles sharing one act-frag set (2 indep chains);
// grid doubled vs nlayer4 for TLP (2-3 blocks/CU)
template<int KS, int CTP>   // CTP = co-tile pairs per node row
__global__ __launch_bounds__(256) void nlayer2(const unsigned short* __restrict__ W,
        const float* __restrict__ bias, const unsigned short* __restrict__ actin,
        unsigned short* __restrict__ actout, int outs) {
    int wave = threadIdx.x >> 6, lane = threadIdx.x & 63;
    int id = blockIdx.x * 4 + wave;
    int nt = id / CTP, cp = id - nt * CTP;
    int r = lane & 15, g = lane >> 4;
    const unsigned short* arow = actin + (size_t)(nt * 16 + r) * (KS * 32) + g * 8;
    bf16x8 afr[KS];
    #pragma unroll
    for (int ks = 0; ks < KS; ks++) afr[ks] = *(const bf16x8*)(arow + ks * 32);
    const unsigned short* w0 = W + (cp * 32 + r) * (KS * 32) + g * 8;
    const unsigned short* w1 = w0 + 16 * KS * 32;
    f32x4 aA = {0.f,0.f,0.f,0.f}, aB = {0.f,0.f,0.f,0.f};
    #pragma unroll
    for (int ks = 0; ks < KS; ks++) {
        aA = __builtin_amdgcn_mfma_f32_16x16x32_bf16(*(const bf16x8*)(w0 + ks * 32), afr[ks], aA, 0, 0, 0);
        aB = __builtin_amdgcn_mfma_f32_16x16x32_bf16(*(const bf16x8*)(w1 + ks * 32), afr[ks], aB, 0, 0, 0);
    }
    f32x4 b0 = *(const f32x4*)(bias + cp * 32 + g * 4);
    f32x4 b1 = *(const f32x4*)(bias + cp * 32 + 16 + g * 4);
    uint2 s0, s1;
    s0.x = cvt2(fmaxf(aA[0] + b0[0], 0.f), fmaxf(aA[1] + b0[1], 0.f));
    s0.y = cvt2(fmaxf(aA[2] + b0[2], 0.f), fmaxf(aA[3] + b0[3], 0.f));
    s1.x = cvt2(fmaxf(aB[0] + b1[0], 0.f), fmaxf(aB[1] + b1[1], 0.f));
    s1.y = cvt2(fmaxf(aB[2] + b1[2], 0.f), fmaxf(aB[3] + b1[3], 0.f));
    *(uint2*)(actout + (size_t)(nt * 16 + r) * outs + cp * 32 + g * 4) = s0;
    *(uint2*)(actout + (size_t)(nt * 16 + r) * outs + cp * 32 + 16 + g * 4) = s1;
}

// last node layer, STREAMING (no act residency -> no spill):
// wave = 16 nodes x 32 couts (2 chains), K=1184 streamed; + global max over nodes
__global__ __launch_bounds__(256) void nlayer_max_s(const unsigned short* __restrict__ W,
        const float* __restrict__ bias, const unsigned short* __restrict__ actin,
        float* __restrict__ out) {
    int wave = threadIdx.x >> 6, lane = threadIdx.x & 63;
    int id = blockIdx.x * 4 + wave;          // 4096 waves
    int nt = id >> 5, cp = id & 31;          // nt: 0..127 (16 nodes), cp: 0..31 (32 couts)
    int r = lane & 15, g = lane >> 4;
    const unsigned short* arow = actin + (size_t)(nt * 16 + r) * 1184 + g * 8;
    const unsigned short* w0 = W + (size_t)(cp * 32 + r) * 1184 + g * 8;
    const unsigned short* w1 = w0 + 16 * 1184;
    f32x4 a0 = {0.f, 0.f, 0.f, 0.f}, a1 = {0.f, 0.f, 0.f, 0.f};
    #pragma unroll 4
    for (int ks = 0; ks < 37; ks++) {
        bf16x8 av = *(const bf16x8*)(arow + ks * 32);
        a0 = __builtin_amdgcn_mfma_f32_16x16x32_bf16(*(const bf16x8*)(w0 + ks * 32), av, a0, 0, 0, 0);
        a1 = __builtin_amdgcn_mfma_f32_16x16x32_bf16(*(const bf16x8*)(w1 + ks * 32), av, a1, 0, 0, 0);
    }
    int b = nt >> 4;
    #pragma unroll
    for (int c = 0; c < 2; c++) {
        f32x4 acc = c ? a1 : a0;
        f32x4 b4 = *(const f32x4*)(bias + cp * 32 + c * 16 + g * 4);
        #pragma unroll
        for (int i = 0; i < 4; i++) {
            float v = fmaxf(acc[i] + b4[i], 0.f);
            v = fmaxf(v, __shfl_xor(v, 1));
            v = fmaxf(v, __shfl_xor(v, 2));
            v = fmaxf(v, __shfl_xor(v, 4));
            v = fmaxf(v, __shfl_xor(v, 8));
            if (r == 0)
                atomicMax((int*)&out[b * 1024 + cp * 32 + c * 16 + g * 4 + i],
                          __float_as_int(v));
        }
    }
}

extern "C" void kernel_launch(void* const* d_in, const int* in_sizes, int n_in,
                              void* d_out, int out_size, void* d_ws, size_t ws_size,
                              hipStream_t stream) {
    (void)in_sizes; (void)n_in; (void)out_size; (void)ws_size;
    const float* x    = (const float*)d_in[0];
    const float* node = (const float*)d_in[2];
    const float* fpw[4] = {(const float*)d_in[4], (const float*)d_in[6],
                           (const float*)d_in[8], (const float*)d_in[10]};
    const float* fpb[4] = {(const float*)d_in[5], (const float*)d_in[7],
                           (const float*)d_in[9], (const float*)d_in[11]};
    const float* fnw[4] = {(const float*)d_in[12], (const float*)d_in[14],
                           (const float*)d_in[16], (const float*)d_in[18]};
    const float* fnb[4] = {(const float*)d_in[13], (const float*)d_in[15],
                           (const float*)d_in[17], (const float*)d_in[19]};
    float* ws  = (float*)d_ws;
    float* out = (float*)d_out;
    unsigned short* wb   = (unsigned short*)(ws + OFF_WBF);
    unsigned short* fin2 = (unsigned short*)(ws + OFF_FIN2);
    unsigned short* h0   = (unsigned short*)(ws + OFF_H0);
    unsigned short* h1   = (unsigned short*)(ws + OFF_H1);
    unsigned short* catb = (unsigned short*)(ws + OFF_CAT);

    hipMemsetAsync(ws, 0, (size_t)ZERO_COUNT * 4, stream);
    hipMemsetAsync(out, 0, (size_t)B_ * 1024 * 4, stream);

    knn_setup<<<128 + 2048, 256, 0, stream>>>(
        x, node, (int*)(ws + OFF_KNN), ws + OFF_COUNTS, ws + OFF_SUMS,
        fpw[0], fpw[1], fpw[2], fpw[3], fnw[0], fnw[1], fnw[2], fnw[3],
        wb, ws + OFF_W3X);
    prep<<<B_, 256, 0, stream>>>(
        ws + OFF_COUNTS, ws + OFF_SUMS, (int*)(ws + OFF_KNN),
        ws + OFF_CM, (int*)(ws + OFF_SORTED), (int*)(ws + OFF_MSORT));
    mlp1m<<<dim3(KNN_ * N_ / 64, B_), 256, 0, stream>>>(
        x, ws + OFF_CM, (int*)(ws + OFF_SORTED), (int*)(ws + OFF_MSORT), wb,
        (const float4*)(ws + OFF_W3X),
        fpb[0], fpb[1], fpb[2], fpb[3], ws + OFF_NODEMAX, ws + OFF_FIRST0);
    build_fin2<<<3328, 256, 0, stream>>>(
        ws + OFF_CM, ws + OFF_COUNTS, ws + OFF_NODEMAX, ws + OFF_FIRST0, fin2, catb);
    nlayer2<13, 16><<<512,  256, 0, stream>>>(wb + O_V0, fnb[0], fin2, h0, 512);
    nlayer2<16, 16><<<512,  256, 0, stream>>>(wb + O_V1, fnb[1], h0, h1, 512);
    nlayer2<16, 24><<<768,  256, 0, stream>>>(wb + O_V2, fnb[2], h1, catb, 1184);
    nlayer_max_s<<<1024, 256, 0, stream>>>(wb + O_V3, fnb[3], catb, out);
}

// Round 14
// 196.051 us; speedup vs baseline: 1.2062x; 1.0270x over previous
//
#include <hip/hip_runtime.h>
#include <math.h>

#define B_   8
#define N_   4096
#define M_   256
#define KNN_ 3

// ---- workspace layout (float element offsets), disjoint unless noted ----
#define OFF_COUNTS   0          // [4 rep][8][256] f32 (atomic; rep-combined into rep0 by prep)
#define OFF_SUMS     8192       // [4 rep][8][256][3] f32
#define ZERO_COUNT   32768      // memset range #1 (counts+sums)
#define OFF_CM       32768      // [8][3][256] f32
#define OFF_NODEMAX  38912      // [8][256][384] f32 (atomicMax as int) ; H0 aliases (phase2)
#define OFF_H0       38912      // ushort [2048][512] (V0 out; nodemax dead after build_fin2)
#define OFF_FIRST0   825344     // [8][384] f32
#define OFF_KNN      828416     // [8][4096][3] int ; CATB aliases (phase2)
#define OFF_CATB     828416     // ushort [2048][768] (V2 out; knn/sorted/msort dead after mlp1m)
#define OFF_SORTED   926720     // [8][12288] int
#define OFF_MSORT    1025024    // [8][12288] int
#define OFF_FIN2     1614848    // ushort [2048][416] (lives until V3)
#define OFF_H1       2040832    // ushort [2048][512]
#define OFF_WBF      2565120    // bf16 weights (ushort)
#define OFF_W3X      3682304    // f32x4 [384] (W3 cols 256..258); end 3683840 f ≈ 14.74 MB
// bf16 padded weight offsets (USHORT units, relative to wb base; contiguous)
#define O_W0 0         // 64   x 32
#define O_W1 2048      // 128  x 64
#define O_W2 10240     // 256  x 128
#define O_W3 43008     // 384  x 288
#define O_V0 153600    // 512  x 416
#define O_V1 366592    // 512  x 512
#define O_V2 628736    // 768  x 512
#define O_V3 1021952   // 1024 x 1184
#define W_TOTAL 2234368

typedef short  bf16x8 __attribute__((ext_vector_type(8)));
typedef float  f32x4  __attribute__((ext_vector_type(4)));
typedef float  f32x16 __attribute__((ext_vector_type(16)));

__device__ __forceinline__ unsigned short f2b(float f) {
    unsigned u = __float_as_uint(f);
    return (unsigned short)((u + 0x7FFFu + ((u >> 16) & 1u)) >> 16);
}
__device__ __forceinline__ unsigned cvt2(float lo, float hi) {
    unsigned r;
    asm("v_cvt_pk_bf16_f32 %0, %1, %2" : "=v"(r) : "v"(lo), "v"(hi));
    return r;
}
__device__ __forceinline__ f32x16 zero16() {
    f32x16 z;
    #pragma unroll
    for (int i = 0; i < 16; i++) z[i] = 0.f;
    return z;
}

// fused: blocks 0..127 = KNN assign (4-replica atomics); blocks 128+ = weight pad + w3x
__global__ __launch_bounds__(256) void knn_setup(
        const float* __restrict__ x, const float* __restrict__ node,
        int* __restrict__ knn, float* __restrict__ counts, float* __restrict__ sums,
        const float* s0, const float* s1, const float* s2, const float* s3,
        const float* s4, const float* s5, const float* s6, const float* s7,
        unsigned short* __restrict__ dst, float* __restrict__ w3x) {
    __shared__ float nd0[M_], nd1[M_], nd2[M_], nn2[M_];
    int t = threadIdx.x;
    if (blockIdx.x < 128) {
        int b = blockIdx.x >> 4, xblk = blockIdx.x & 15;
        int rep = blockIdx.x & 3;
        {
            float c0 = node[(b * 3 + 0) * M_ + t];
            float c1 = node[(b * 3 + 1) * M_ + t];
            float c2 = node[(b * 3 + 2) * M_ + t];
            nd0[t] = c0; nd1[t] = c1; nd2[t] = c2;
            nn2[t] = c0 * c0 + c1 * c1 + c2 * c2;
        }
        __syncthreads();
        int n = xblk * 256 + t;
        float x0 = x[(b * 3 + 0) * N_ + n];
        float x1 = x[(b * 3 + 1) * N_ + n];
        float x2 = x[(b * 3 + 2) * N_ + n];
        float xx = x0 * x0 + x1 * x1 + x2 * x2;
        float d0 = 1e30f, d1 = 1e30f, d2b = 1e30f;
        int i0 = 0, i1 = 0, i2 = 0;
        for (int m = 0; m < M_; m++) {
            float cross = x0 * nd0[m] + x1 * nd1[m] + x2 * nd2[m];
            float d = xx + nn2[m] - 2.f * cross;
            bool c0 = d < d0, c1 = d < d1, c2 = d < d2b;
            d2b = c1 ? d1 : (c2 ? d : d2b);
            i2  = c1 ? i1 : (c2 ? m : i2);
            d1  = c0 ? d0 : (c1 ? d : d1);
            i1  = c0 ? i0 : (c1 ? m : i1);
            d0  = c0 ? d  : d0;
            i0  = c0 ? m  : i0;
        }
        int base = (b * N_ + n) * 3;
        knn[base + 0] = i0; knn[base + 1] = i1; knn[base + 2] = i2;
        float* cnt = counts + rep * 2048;
        float* sm  = sums + rep * 6144;
        int mm[3] = {i0, i1, i2};
        #pragma unroll
        for (int k = 0; k < 3; k++) {
            int m = mm[k];
            atomicAdd(&cnt[b * M_ + m], 1.f);
            atomicAdd(&sm[(b * M_ + m) * 3 + 0], x0);
            atomicAdd(&sm[(b * M_ + m) * 3 + 1], x1);
            atomicAdd(&sm[(b * M_ + m) * 3 + 2], x2);
        }
    } else {
        int i = (blockIdx.x - 128) * 256 + t;
        int st = (gridDim.x - 128) * 256;
        for (int j = i; j < 1536; j += st) {
            int ch = j >> 2, c = j & 3;
            w3x[j] = (c < 3) ? s3[ch * 259 + 256 + c] : 0.f;
        }
        for (; i < W_TOTAL; i += st) {
            unsigned short v;
            if (i < O_W1) {
                int loc = i, co = loc >> 5, k = loc & 31;
                v = (k < 3) ? f2b(s0[co * 3 + k]) : (unsigned short)0;
            } else if (i < O_W2) {
                int loc = i - O_W1, co = loc >> 6, k = loc & 63;
                v = f2b(s1[co * 64 + k]);
            } else if (i < O_W3) {
                int loc = i - O_W2, co = loc >> 7, k = loc & 127;
                v = f2b(s2[co * 128 + k]);
            } else if (i < O_V0) {
                int loc = i - O_W3, co = loc / 288u, k = loc - co * 288;
                v = (k < 259) ? f2b(s3[co * 259 + k]) : (unsigned short)0;
            } else if (i < O_V1) {
                int loc = i - O_V0, co = loc / 416u, k = loc - co * 416;
                v = (k < 387) ? f2b(s4[co * 387 + k]) : (unsigned short)0;
            } else if (i < O_V2) {
                int loc = i - O_V1, co = loc >> 9, k = loc & 511;
                v = f2b(s5[co * 512 + k]);
            } else if (i < O_V3) {
                int loc = i - O_V2, co = loc >> 9, k = loc & 511;
                v = f2b(s6[co * 512 + k]);
            } else {
                int loc = i - O_V3, co = loc / 1184u, k = loc - co * 1184;
                v = (k < 1155) ? f2b(s7[co * 1155 + k]) : (unsigned short)0;
            }
            dst[i] = v;
        }
    }
}

// merged: replica-sum + cluster means + scan + counting-sort scatter, 1 block/batch
__global__ __launch_bounds__(256) void prep(float* __restrict__ counts,
        const float* __restrict__ sums, const int* __restrict__ knn,
        float* __restrict__ cm, int* __restrict__ sorted, int* __restrict__ msort) {
    __shared__ int tmp[256], offsL[257], cur[256];
    int t = threadIdx.x, b = blockIdx.x;
    float cnt = 0.f, s0 = 0.f, s1 = 0.f, s2 = 0.f;
    #pragma unroll
    for (int rp = 0; rp < 4; rp++) {
        cnt += counts[rp * 2048 + b * M_ + t];
        s0 += sums[rp * 6144 + (b * M_ + t) * 3 + 0];
        s1 += sums[rp * 6144 + (b * M_ + t) * 3 + 1];
        s2 += sums[rp * 6144 + (b * M_ + t) * 3 + 2];
    }
    counts[b * M_ + t] = cnt;   // combined into replica 0 for build_fin2
    float inv = 1.f / (cnt + 1e-5f);
    cm[(b * 3 + 0) * M_ + t] = s0 * inv;
    cm[(b * 3 + 1) * M_ + t] = s1 * inv;
    cm[(b * 3 + 2) * M_ + t] = s2 * inv;
    int v = (int)cnt;
    tmp[t] = v; cur[t] = 0;
    __syncthreads();
    for (int off = 1; off < 256; off <<= 1) {
        int u = (t >= off) ? tmp[t - off] : 0;
        __syncthreads();
        tmp[t] += u;
        __syncthreads();
    }
    offsL[t] = tmp[t] - v;
    if (t == 255) offsL[256] = tmp[255];
    __syncthreads();
    for (int e = t; e < KNN_ * N_; e += 256) {
        int n = e & (N_ - 1), k = e >> 12;
        int m = knn[(b * N_ + n) * 3 + k];
        int pos = atomicAdd(&cur[m], 1);
        int dst = offsL[m] + pos;
        sorted[b * (KNN_ * N_) + dst] = e;
        msort[b * (KNN_ * N_) + dst] = m;
    }
}

// B-stationary layer: wave holds B-frags for ALL 4 p-tiles in regs,
// owns CTW co-tiles, streams W. 4 independent MFMA chains.
template<int KS, int INS, int OUTS, int CTW>
__device__ __forceinline__ void layerB(const unsigned short* __restrict__ Wg,
        const float* __restrict__ bias, const unsigned short* actin,
        unsigned short* actout, int wave, int lane) {
    int r = lane & 15, g = lane >> 4;
    bf16x8 bfr[4][KS];
    #pragma unroll
    for (int pt = 0; pt < 4; pt++) {
        const unsigned short* arow = actin + (pt * 16 + r) * INS + g * 8;
        #pragma unroll
        for (int ks = 0; ks < KS; ks++)
            bfr[pt][ks] = *(const bf16x8*)(arow + ks * 32);
    }
    #pragma unroll
    for (int c = 0; c < CTW; c++) {
        int ct = wave * CTW + c;
        const unsigned short* wrow = Wg + (ct * 16 + r) * (KS * 32) + g * 8;
        f32x4 acc[4];
        #pragma unroll
        for (int pt = 0; pt < 4; pt++) acc[pt] = (f32x4){0.f, 0.f, 0.f, 0.f};
        #pragma unroll
        for (int ks = 0; ks < KS; ks++) {
            bf16x8 wv = *(const bf16x8*)(wrow + ks * 32);
            #pragma unroll
            for (int pt = 0; pt < 4; pt++)
                acc[pt] = __builtin_amdgcn_mfma_f32_16x16x32_bf16(wv, bfr[pt][ks], acc[pt], 0, 0, 0);
        }
        f32x4 b4 = *(const f32x4*)(bias + ct * 16 + g * 4);
        #pragma unroll
        for (int pt = 0; pt < 4; pt++) {
            uint2 s;
            s.x = cvt2(fmaxf(acc[pt][0] + b4[0], 0.f), fmaxf(acc[pt][1] + b4[1], 0.f));
            s.y = cvt2(fmaxf(acc[pt][2] + b4[2], 0.f), fmaxf(acc[pt][3] + b4[3], 0.f));
            *(uint2*)(actout + (pt * 16 + r) * OUTS + ct * 16 + g * 4) = s;
        }
    }
}

// MFMA point-MLP over sorted entries, 64 points/block, ~52.5 KB LDS (3 blocks/CU).
// L4: swapped-operand 32x32x16 MFMA; seg-max in-register per lane.
__global__ __launch_bounds__(256, 3) void mlp1m(
        const float* __restrict__ x, const float* __restrict__ cm,
        const int* __restrict__ sorted, const int* __restrict__ msort,
        const unsigned short* __restrict__ wb, const float4* __restrict__ w3x,
        const float* __restrict__ bb0, const float* __restrict__ bb1,
        const float* __restrict__ bb2, const float* __restrict__ bb3,
        float* __restrict__ node_max, float* __restrict__ first0) {
    __shared__ __align__(16) char smem[50688];
    unsigned short* inb = (unsigned short*)smem;
    unsigned short* a1  = (unsigned short*)smem;
    unsigned short* a0  = (unsigned short*)(smem + 16896);
    unsigned short* cat = (unsigned short*)(smem + 16896);
    __shared__ float4 xdf[64];
    __shared__ int segm[65], segstart[66];
    __shared__ int nseg, p0loc;
    int t = threadIdx.x, b = blockIdx.y, lane = t & 63, wave = t >> 6;
    int e0 = blockIdx.x * 64;
    for (int e = t; e < 1280; e += 256) ((unsigned*)inb)[e] = 0u;   // zero inb [64][40]
    __syncthreads();
    if (t < 64) {   // wave 0: per-point init + ballot segment scan
        int p = t;
        if (p == 0) p0loc = -1;
        int j = sorted[b * 12288 + e0 + p];
        int m = msort[b * 12288 + e0 + p];
        int n = j & (N_ - 1);
        float xd0 = x[(b * 3 + 0) * N_ + n] - cm[(b * 3 + 0) * M_ + m];
        float xd1 = x[(b * 3 + 1) * N_ + n] - cm[(b * 3 + 1) * M_ + m];
        float xd2 = x[(b * 3 + 2) * N_ + n] - cm[(b * 3 + 2) * M_ + m];
        xdf[p] = make_float4(xd0, xd1, xd2, 0.f);
        inb[p * 40 + 0] = f2b(xd0);
        inb[p * 40 + 1] = f2b(xd1);
        inb[p * 40 + 2] = f2b(xd2);
        int prev = __shfl_up(m, 1);
        bool flag = (p == 0) || (m != prev);
        unsigned long long mk = __ballot(flag);
        int sid = __popcll(mk & ((1ull << p) - 1ull));
        if (flag) { segstart[sid] = p; segm[sid] = m; }
        if (p == 63) { int ns2 = __popcll(mk); nseg = ns2; segstart[ns2] = 64; }
        if (j == 0) p0loc = p;
    }
    __syncthreads();
    layerB<1, 40, 72, 1>(wb + O_W0, bb0, inb, a0, wave, lane);     // inb -> a0
    __syncthreads();
    layerB<2, 72, 132, 2>(wb + O_W1, bb1, a0, a1, wave, lane);     // a0 -> a1 (over inb)
    __syncthreads();
    layerB<4, 132, 264, 4>(wb + O_W2, bb2, a1, cat, wave, lane);   // a1 -> cat (over a0)
    __syncthreads();
    // ---- L4: 12 co-tiles of 32 x 4 waves (3 each), 2 point-halves, K=256 ----
    int l31 = lane & 31, half = lane >> 5;
    f32x16 acc[6];   // [c3*2 + ph]
    #pragma unroll
    for (int q = 0; q < 6; q++) acc[q] = zero16();
    {
        const unsigned short* arow0 = cat + l31 * 264 + half * 8;
        const unsigned short* arow1 = cat + (32 + l31) * 264 + half * 8;
        const unsigned short* wrowb = wb + O_W3 + (wave * 96 + l31) * 288 + half * 8;
        #pragma unroll
        for (int ks = 0; ks < 16; ks++) {
            bf16x8 aA = *(const bf16x8*)(arow0 + ks * 16);
            bf16x8 aB = *(const bf16x8*)(arow1 + ks * 16);
            #pragma unroll
            for (int c3 = 0; c3 < 3; c3++) {
                bf16x8 wv = *(const bf16x8*)(wrowb + c3 * 32 * 288 + ks * 16);
                acc[c3 * 2 + 0] = __builtin_amdgcn_mfma_f32_32x32x16_bf16(aA, wv, acc[c3 * 2 + 0], 0, 0, 0);
                acc[c3 * 2 + 1] = __builtin_amdgcn_mfma_f32_32x32x16_bf16(aB, wv, acc[c3 * 2 + 1], 0, 0, 0);
            }
        }
    }
    int ns = nseg, p0l = p0loc;
    float bias3[3]; float4 wx3[3];
    #pragma unroll
    for (int c3 = 0; c3 < 3; c3++) {
        bias3[c3] = bb3[(wave * 3 + c3) * 32 + l31];
        wx3[c3]   = w3x[(wave * 3 + c3) * 32 + l31];
    }
    #pragma unroll
    for (int ph = 0; ph < 2; ph++) {
        #pragma unroll
        for (int rg = 0; rg < 16; rg++) {
            int row = ph * 32 + (rg & 3) + 8 * (rg >> 2) + 4 * half;
            float4 xv = xdf[row];
            #pragma unroll
            for (int c3 = 0; c3 < 3; c3++) {
                float s = acc[c3 * 2 + ph][rg] + bias3[c3]
                        + wx3[c3].x * xv.x + wx3[c3].y * xv.y + wx3[c3].z * xv.z;
                acc[c3 * 2 + ph][rg] = fmaxf(s, 0.f);
            }
        }
    }
    if (p0l >= 0) {
        #pragma unroll
        for (int ph = 0; ph < 2; ph++)
            #pragma unroll
            for (int rg = 0; rg < 16; rg++) {
                int row = ph * 32 + (rg & 3) + 8 * (rg >> 2) + 4 * half;
                if (row == p0l) {
                    #pragma unroll
                    for (int c3 = 0; c3 < 3; c3++)
                        first0[b * 384 + (wave * 3 + c3) * 32 + l31] = acc[c3 * 2 + ph][rg];
                }
            }
    }
    for (int s = 0; s < ns; s++) {
        int s0 = segstart[s], s1 = segstart[s + 1];
        float m0 = 0.f, m1 = 0.f, m2 = 0.f;
        if (s0 < 32) {
            #pragma unroll
            for (int rg = 0; rg < 16; rg++) {
                int row = (rg & 3) + 8 * (rg >> 2) + 4 * half;
                bool in = (row >= s0) && (row < s1);
                m0 = fmaxf(m0, in ? acc[0][rg] : 0.f);
                m1 = fmaxf(m1, in ? acc[2][rg] : 0.f);
                m2 = fmaxf(m2, in ? acc[4][rg] : 0.f);
            }
        }
        if (s1 > 32) {
            #pragma unroll
            for (int rg = 0; rg < 16; rg++) {
                int row = 32 + (rg & 3) + 8 * (rg >> 2) + 4 * half;
                bool in = (row >= s0) && (row < s1);
                m0 = fmaxf(m0, in ? acc[1][rg] : 0.f);
                m1 = fmaxf(m1, in ? acc[3][rg] : 0.f);
                m2 = fmaxf(m2, in ? acc[5][rg] : 0.f);
            }
        }
        m0 = fmaxf(m0, __shfl_xor(m0, 32));
        m1 = fmaxf(m1, __shfl_xor(m1, 32));
        m2 = fmaxf(m2, __shfl_xor(m2, 32));
        if (lane < 32) {
            float* dstp = &node_max[(size_t)(b * M_ + segm[s]) * 384 + wave * 96];
            atomicMax((int*)(dstp + l31),      __float_as_int(m0));
            atomicMax((int*)(dstp + 32 + l31), __float_as_int(m1));
            atomicMax((int*)(dstp + 64 + l31), __float_as_int(m2));
        }
    }
}

// masked node features -> bf16 fin2 [2048][416] only (V3 reads fin2 directly)
__global__ void build_fin2(const float* __restrict__ cm, const float* __restrict__ counts,
                           const float* __restrict__ nmax, const float* __restrict__ first0,
                           unsigned short* __restrict__ fin2) {
    int tot = 2048 * 416;
    int i = blockIdx.x * blockDim.x + threadIdx.x;
    int st = gridDim.x * blockDim.x;
    for (; i < tot; i += st) {
        int n = i / 416, ch = i - n * 416;
        int b = n >> 8, m = n & 255;
        float v = 0.f;
        if (ch < 3) v = cm[(b * 3 + ch) * M_ + m];
        else if (ch < 387)
            v = (counts[n] > 0.f) ? nmax[(size_t)n * 384 + (ch - 3)]
                                  : first0[b * 384 + (ch - 3)];
        fin2[n * 416 + ch] = f2b(v);
    }
}

// node-MLP layer: one wave = 4 co-tiles sharing one act-frag set (4 indep chains)
template<int KS, int CTQ>
__global__ __launch_bounds__(256, 2) void nlayer4(const unsigned short* __restrict__ W,
        const float* __restrict__ bias, const unsigned short* __restrict__ actin,
        unsigned short* __restrict__ actout, int outs) {
    int wave = threadIdx.x >> 6, lane = threadIdx.x & 63;
    int id = blockIdx.x * 4 + wave;
    int nt = id / CTQ, cq = id - nt * CTQ;
    int r = lane & 15, g = lane >> 4;
    const unsigned short* arow = actin + (size_t)(nt * 16 + r) * (KS * 32) + g * 8;
    bf16x8 afr[KS];
    #pragma unroll
    for (int ks = 0; ks < KS; ks++) afr[ks] = *(const bf16x8*)(arow + ks * 32);
    const unsigned short* w0 = W + (cq * 64 + r) * (KS * 32) + g * 8;
    f32x4 acc[4];
    #pragma unroll
    for (int c = 0; c < 4; c++) acc[c] = (f32x4){0.f, 0.f, 0.f, 0.f};
    #pragma unroll
    for (int ks = 0; ks < KS; ks++) {
        #pragma unroll
        for (int c = 0; c < 4; c++) {
            bf16x8 wv = *(const bf16x8*)(w0 + c * 16 * KS * 32 + ks * 32);
            acc[c] = __builtin_amdgcn_mfma_f32_16x16x32_bf16(wv, afr[ks], acc[c], 0, 0, 0);
        }
    }
    #pragma unroll
    for (int c = 0; c < 4; c++) {
        f32x4 b4 = *(const f32x4*)(bias + cq * 64 + c * 16 + g * 4);
        uint2 s;
        s.x = cvt2(fmaxf(acc[c][0] + b4[0], 0.f), fmaxf(acc[c][1] + b4[1], 0.f));
        s.y = cvt2(fmaxf(acc[c][2] + b4[2], 0.f), fmaxf(acc[c][3] + b4[3], 0.f));
        *(uint2*)(actout + (size_t)(nt * 16 + r) * outs + cq * 64 + c * 16 + g * 4) = s;
    }
}

// last node layer, STREAMING from [catb(768) | fin2(416)]; wave = 16 nodes x 32 couts;
// + global max over nodes
__global__ __launch_bounds__(256) void nlayer_max_s(const unsigned short* __restrict__ W,
        const float* __restrict__ bias, const unsigned short* __restrict__ catb,
        const unsigned short* __restrict__ fin2, float* __restrict__ out) {
    int wave = threadIdx.x >> 6, lane = threadIdx.x & 63;
    int id = blockIdx.x * 4 + wave;          // 4096 waves
    int nt = id >> 5, cp = id & 31;
    int r = lane & 15, g = lane >> 4;
    const unsigned short* arow0 = catb + (size_t)(nt * 16 + r) * 768 + g * 8;
    const unsigned short* arow1 = fin2 + (size_t)(nt * 16 + r) * 416 + g * 8;
    const unsigned short* w0 = W + (size_t)(cp * 32 + r) * 1184 + g * 8;
    const unsigned short* w1 = w0 + 16 * 1184;
    f32x4 a0 = {0.f, 0.f, 0.f, 0.f}, a1 = {0.f, 0.f, 0.f, 0.f};
    #pragma unroll 4
    for (int ks = 0; ks < 24; ks++) {
        bf16x8 av = *(const bf16x8*)(arow0 + ks * 32);
        a0 = __builtin_amdgcn_mfma_f32_16x16x32_bf16(*(const bf16x8*)(w0 + ks * 32), av, a0, 0, 0, 0);
        a1 = __builtin_amdgcn_mfma_f32_16x16x32_bf16(*(const bf16x8*)(w1 + ks * 32), av, a1, 0, 0, 0);
    }
    #pragma unroll 4
    for (int ks = 0; ks < 13; ks++) {
        bf16x8 av = *(const bf16x8*)(arow1 + ks * 32);
        a0 = __builtin_amdgcn_mfma_f32_16x16x32_bf16(*(const bf16x8*)(w0 + (24 + ks) * 32), av, a0, 0, 0, 0);
        a1 = __builtin_amdgcn_mfma_f32_16x16x32_bf16(*(const bf16x8*)(w1 + (24 + ks) * 32), av, a1, 0, 0, 0);
    }
    int b = nt >> 4;
    #pragma unroll
    for (int c = 0; c < 2; c++) {
        f32x4 acc = c ? a1 : a0;
        f32x4 b4 = *(const f32x4*)(bias + cp * 32 + c * 16 + g * 4);
        #pragma unroll
        for (int i = 0; i < 4; i++) {
            float v = fmaxf(acc[i] + b4[i], 0.f);
            v = fmaxf(v, __shfl_xor(v, 1));
            v = fmaxf(v, __shfl_xor(v, 2));
            v = fmaxf(v, __shfl_xor(v, 4));
            v = fmaxf(v, __shfl_xor(v, 8));
            if (r == 0)
                atomicMax((int*)&out[b * 1024 + cp * 32 + c * 16 + g * 4 + i],
                          __float_as_int(v));
        }
    }
}

extern "C" void kernel_launch(void* const* d_in, const int* in_sizes, int n_in,
                              void* d_out, int out_size, void* d_ws, size_t ws_size,
                              hipStream_t stream) {
    (void)in_sizes; (void)n_in; (void)out_size; (void)ws_size;
    const float* x    = (const float*)d_in[0];
    const float* node = (const float*)d_in[2];
    const float* fpw[4] = {(const float*)d_in[4], (const float*)d_in[6],
                           (const float*)d_in[8], (const float*)d_in[10]};
    const float* fpb[4] = {(const float*)d_in[5], (const float*)d_in[7],
                           (const float*)d_in[9], (const float*)d_in[11]};
    const float* fnw[4] = {(const float*)d_in[12], (const float*)d_in[14],
                           (const float*)d_in[16], (const float*)d_in[18]};
    const float* fnb[4] = {(const float*)d_in[13], (const float*)d_in[15],
                           (const float*)d_in[17], (const float*)d_in[19]};
    float* ws  = (float*)d_ws;
    float* out = (float*)d_out;
    unsigned short* wb   = (unsigned short*)(ws + OFF_WBF);
    unsigned short* fin2 = (unsigned short*)(ws + OFF_FIN2);
    unsigned short* h0   = (unsigned short*)(ws + OFF_H0);
    unsigned short* h1   = (unsigned short*)(ws + OFF_H1);
    unsigned short* catb = (unsigned short*)(ws + OFF_CATB);

    hipMemsetAsync(ws, 0, (size_t)ZERO_COUNT * 4, stream);                       // counts+sums
    hipMemsetAsync(ws + OFF_NODEMAX, 0, (size_t)(B_ * M_ * 384) * 4, stream);    // atomicMax targets

    knn_setup<<<128 + 2048, 256, 0, stream>>>(
        x, node, (int*)(ws + OFF_KNN), ws + OFF_COUNTS, ws + OFF_SUMS,
        fpw[0], fpw[1], fpw[2], fpw[3], fnw[0], fnw[1], fnw[2], fnw[3],
        wb, ws + OFF_W3X);
    prep<<<B_, 256, 0, stream>>>(
        ws + OFF_COUNTS, ws + OFF_SUMS, (int*)(ws + OFF_KNN),
        ws + OFF_CM, (int*)(ws + OFF_SORTED), (int*)(ws + OFF_MSORT));
    mlp1m<<<dim3(KNN_ * N_ / 64, B_), 256, 0, stream>>>(
        x, ws + OFF_CM, (int*)(ws + OFF_SORTED), (int*)(ws + OFF_MSORT), wb,
        (const float4*)(ws + OFF_W3X),
        fpb[0], fpb[1], fpb[2], fpb[3], ws + OFF_NODEMAX, ws + OFF_FIRST0);
    build_fin2<<<3328, 256, 0, stream>>>(
        ws + OFF_CM, ws + OFF_COUNTS, ws + OFF_NODEMAX, ws + OFF_FIRST0, fin2);
    nlayer4<13, 8><<<256,  256, 0, stream>>>(wb + O_V0, fnb[0], fin2, h0, 512);
    nlayer4<16, 8><<<256,  256, 0, stream>>>(wb + O_V1, fnb[1], h0, h1, 512);
    nlayer4<16, 12><<<384, 256, 0, stream>>>(wb + O_V2, fnb[2], h1, catb, 768);
    nlayer_max_s<<<1024, 256, 0, stream>>>(wb + O_V3, fnb[3], catb, fin2, out);
}